// Round 3
// baseline (656.507 us; speedup 1.0000x reference)
//
#include <hip/hip_runtime.h>
#include <hip/hip_bf16.h>

// x [B=4][C=256][N=4096] fp32 -> attention [B][N][N] fp32 (row softmax of cosine sim)
#define BATCH 4
#define CDIM  256
#define NTOK  4096

#define BM 32      // rows per block
#define BN 128     // cols per ct tile
#define TCHUNKS 128   // per sweep: 32 ct * 4 ck (chunk = 128 tok x 64 k = 16 KB)

typedef short bf16x8 __attribute__((ext_vector_type(8)));
typedef float floatx4 __attribute__((ext_vector_type(4)));
typedef unsigned int uintx4 __attribute__((ext_vector_type(4)));
typedef unsigned int u32;

#define WAITV0  asm volatile("s_waitcnt vmcnt(0)" ::: "memory")
#define WAITV2  asm volatile("s_waitcnt vmcnt(2)" ::: "memory")
#define WAITV4  asm volatile("s_waitcnt vmcnt(4)" ::: "memory")
#define WAITV12 asm volatile("s_waitcnt vmcnt(12)" ::: "memory")
#define MEMFENCE asm volatile("" ::: "memory")

__device__ inline u32 f2bf1(float f) {
    u32 u = __float_as_uint(f);
    u += 0x7fffu + ((u >> 16) & 1u);   // RTNE
    return u >> 16;
}
__device__ inline u32 f2bf2(float lo, float hi) { return f2bf1(lo) | (f2bf1(hi) << 16); }

__device__ inline void gload_lds16(const short* g, short* l) {
    __builtin_amdgcn_global_load_lds(
        (const __attribute__((address_space(1))) u32*)g,
        (__attribute__((address_space(3))) u32*)l, 16, 0, 0);
}

// ---------- prep: x [B][C][N] f32 -> xn [B][N][C] bf16, rows normalized to unit L2 ----------
#define TT 32
__global__ __launch_bounds__(256) void prep_kernel(const float* __restrict__ x,
                                                   short* __restrict__ xn) {
    __shared__ float tile[TT][CDIM + 2];
    __shared__ float part[8][TT];
    __shared__ float rinv_s[TT];
    const int tid = threadIdx.x;
    const int blk = blockIdx.x;            // 0..511
    const int b = blk >> 7;
    const int t0 = (blk & 127) * TT;
    const float* xb = x + (size_t)b * CDIM * NTOK;
    const int ti = tid & 31, cq = tid >> 5;
    float ss = 0.f;
    for (int c = cq; c < CDIM; c += 8) {
        float v = xb[(size_t)c * NTOK + t0 + ti];
        tile[ti][c] = v;
        ss += v * v;
    }
    part[cq][ti] = ss;
    __syncthreads();
    if (tid < TT) {
        float s = 0.f;
#pragma unroll
        for (int q = 0; q < 8; ++q) s += part[q][tid];
        rinv_s[tid] = 1.0f / sqrtf(s);
    }
    __syncthreads();
    const int tok = tid >> 3, seg = tid & 7;
    const float ri = rinv_s[tok];
    size_t obase = ((size_t)(b * NTOK + t0 + tok)) * CDIM + seg * 32;
#pragma unroll
    for (int j = 0; j < 4; ++j) {
        u32 w[4];
#pragma unroll
        for (int u = 0; u < 4; ++u) {
            float f0 = tile[tok][seg * 32 + j * 8 + 2 * u] * ri;
            float f1 = tile[tok][seg * 32 + j * 8 + 2 * u + 1] * ri;
            w[u] = f2bf2(f0, f1);
        }
        *(uintx4*)&xn[obase + j * 8] = (uintx4){w[0], w[1], w[2], w[3]};
    }
}

// ---------- fused two-sweep GEMM + softmax, counted-vmcnt pipeline ----------
// Block: 32 rows x 4096 cols, K=256. A in regs. B chunks (128 tok x 64 k = 16 KB)
// in a 4-deep circular LDS buffer, prefetch depth 2, ONE raw s_barrier per chunk.
// LDS XOR-swizzle: 16B-position p of row tr holds logical 16B-chunk (p ^ (tr&7)).
__global__ __launch_bounds__(512, 4) void attn_kernel(const short* __restrict__ xn,
                                                      float* __restrict__ out) {
    __shared__ short Bs[4][128 * 64];       // 4 x 16 KB
    __shared__ float rowsumLds[BM][8];
    const int tid = threadIdx.x;
    const int b = blockIdx.y;
    const int rb = blockIdx.x * BM;
    const short* xnb = xn + (size_t)b * NTOK * CDIM;
    float* outb = out + ((size_t)b << 24);
    const int lane = tid & 63, wid = tid >> 6;     // 8 waves, each owns 16 cols of the ct tile
    const int wc = wid * 16;
    const int r0 = lane & 15, kq = lane >> 4;

    // staging roles: wave w stages rows w*8..w*8+7 (and +64) of the 128-row chunk
    const int trl = (wid << 3) + (lane >> 3);      // 0..63
    const int swz8 = (lane & 7) ^ (lane >> 3);     // inverse-swizzled source 16B-chunk

    // A fragments: rows rb + m*16 + r0, full K=256 in registers
    bf16x8 afr[2][8];
#pragma unroll
    for (int m = 0; m < 2; ++m) {
        const short* arow = xnb + (size_t)(rb + m * 16 + r0) * CDIM;
#pragma unroll
        for (int kc = 0; kc < 8; ++kc)
            afr[m][kc] = *(const bf16x8*)(arow + kc * 32 + kq * 8);
    }

    float psum[2][4] = {{0.f,0.f,0.f,0.f},{0.f,0.f,0.f,0.f}};
    float rinv[2][4];

    auto stage = [&](int t, int buf) {
        const int ct = t >> 2, ck = t & 3;
        const short* s0 = xnb + (size_t)(ct * BN + trl) * CDIM + ck * 64 + swz8 * 8;
        short* d = &Bs[buf][wid << 9];             // rows wid*8.. : byte offset wid*1024
        gload_lds16(s0, d);
        gload_lds16(s0 + 64 * CDIM, d + 4096);     // rows 64+wid*8..
    };

    for (int sweep = 0; sweep < 2; ++sweep) {
        stage(0, 0);
        stage(1, 1);
        floatx4 acc[2];
        acc[0] = (floatx4){0.f, 0.f, 0.f, 0.f};
        acc[1] = (floatx4){0.f, 0.f, 0.f, 0.f};

        for (int t = 0; t < TCHUNKS; ++t) {
            if (t + 2 < TCHUNKS) stage(t + 2, (t + 2) & 3);

            // counted waits: never drain to 0 mid-loop. In sweep 1 the previous
            // ct's 8 stores sit between counted loads at (t&3)<=1 -> allow 12.
            if (t < TCHUNKS - 2) {
                if (sweep == 1 && t >= 4 && (t & 3) <= 1) { WAITV12; } else { WAITV4; }
            } else if (t == TCHUNKS - 2) { WAITV2; } else { WAITV0; }
            __builtin_amdgcn_s_barrier();
            MEMFENCE;

            const short* base = &Bs[t & 3][0];
            const int ck = t & 3;
            __builtin_amdgcn_s_setprio(1);
#pragma unroll
            for (int kk = 0; kk < 2; ++kk) {
                const int p = ((kk << 2) | kq) ^ (r0 & 7);
                bf16x8 bfr = *(const bf16x8*)&base[(wc + r0) * 64 + p * 8];
                acc[0] = __builtin_amdgcn_mfma_f32_16x16x32_bf16(afr[0][ck * 2 + kk], bfr, acc[0], 0, 0, 0);
                acc[1] = __builtin_amdgcn_mfma_f32_16x16x32_bf16(afr[1][ck * 2 + kk], bfr, acc[1], 0, 0, 0);
            }
            __builtin_amdgcn_s_setprio(0);

            if ((t & 3) == 3) {
                const int ct = t >> 2;
                if (sweep == 0) {
#pragma unroll
                    for (int m = 0; m < 2; ++m)
#pragma unroll
                        for (int r = 0; r < 4; ++r)
                            psum[m][r] += __expf(acc[m][r] - 1.f);
                } else {
#pragma unroll
                    for (int m = 0; m < 2; ++m)
#pragma unroll
                        for (int r = 0; r < 4; ++r) {
                            const int row = rb + m * 16 + kq * 4 + r;
                            float v = __expf(acc[m][r] - 1.f) * rinv[m][r];
                            __builtin_nontemporal_store(v, &outb[((size_t)row << 12) + ct * BN + wc + r0]);
                        }
                }
                acc[0] = (floatx4){0.f, 0.f, 0.f, 0.f};
                acc[1] = (floatx4){0.f, 0.f, 0.f, 0.f};
            }
        } // t

        if (sweep == 0) {
#pragma unroll
            for (int m = 0; m < 2; ++m)
#pragma unroll
                for (int r = 0; r < 4; ++r) {
                    float v = psum[m][r];
                    v += __shfl_xor(v, 1);
                    v += __shfl_xor(v, 2);
                    v += __shfl_xor(v, 4);
                    v += __shfl_xor(v, 8);
                    if (r0 == 0) rowsumLds[m * 16 + kq * 4 + r][wid] = v;
                }
            __syncthreads();
#pragma unroll
            for (int m = 0; m < 2; ++m)
#pragma unroll
                for (int r = 0; r < 4; ++r) {
                    const int row = m * 16 + kq * 4 + r;
                    float s = 0.f;
#pragma unroll
                    for (int w = 0; w < 8; ++w) s += rowsumLds[row][w];
                    rinv[m][r] = 1.0f / s;
                }
        }
    } // sweep
}

extern "C" void kernel_launch(void* const* d_in, const int* in_sizes, int n_in,
                              void* d_out, int out_size, void* d_ws, size_t ws_size,
                              hipStream_t stream) {
    const float* x = (const float*)d_in[0];
    float* out = (float*)d_out;
    short* xn = (short*)d_ws;    // [B][N][C] bf16 = 8 MB

    prep_kernel<<<BATCH * (NTOK / TT), 256, 0, stream>>>(x, xn);

    dim3 grid(NTOK / BM, BATCH);
    attn_kernel<<<grid, 512, 0, stream>>>(xn, out);
}

// Round 4
// 365.675 us; speedup vs baseline: 1.7953x; 1.7953x over previous
//
#include <hip/hip_runtime.h>
#include <hip/hip_bf16.h>

// x [B=4][C=256][N=4096] fp32 -> attention [B][N][N] fp32 (row softmax of cosine sim)
#define BATCH 4
#define CDIM  256
#define NTOK  4096

#define BM 64       // rows per block
#define BN 128      // cols per ct tile
#define NCHUNK 64   // per sweep: 32 ct x 2 k-halves; chunk = 128 tok x 128 k = 32 KB

typedef short bf16x8 __attribute__((ext_vector_type(8)));
typedef float floatx4 __attribute__((ext_vector_type(4)));
typedef unsigned int uintx4 __attribute__((ext_vector_type(4)));
typedef unsigned int u32;

#define WAITV0  asm volatile("s_waitcnt vmcnt(0)" ::: "memory")
#define WAITV4  asm volatile("s_waitcnt vmcnt(4)" ::: "memory")
#define MEMFENCE asm volatile("" ::: "memory")

__device__ inline u32 f2bf1(float f) {
    u32 u = __float_as_uint(f);
    u += 0x7fffu + ((u >> 16) & 1u);   // RTNE
    return u >> 16;
}
__device__ inline u32 f2bf2(float lo, float hi) { return f2bf1(lo) | (f2bf1(hi) << 16); }

__device__ inline void gload_lds16(const short* g, short* l) {
    __builtin_amdgcn_global_load_lds(
        (const __attribute__((address_space(1))) u32*)g,
        (__attribute__((address_space(3))) u32*)l, 16, 0, 0);
}

// ---------- prep: x [B][C][N] f32 -> xn [B][N][C] bf16, rows normalized to unit L2 ----------
#define TT 32
__global__ __launch_bounds__(256) void prep_kernel(const float* __restrict__ x,
                                                   short* __restrict__ xn) {
    __shared__ float tile[TT][CDIM + 2];
    __shared__ float part[8][TT];
    __shared__ float rinv_s[TT];
    const int tid = threadIdx.x;
    const int blk = blockIdx.x;            // 0..511
    const int b = blk >> 7;
    const int t0 = (blk & 127) * TT;
    const float* xb = x + (size_t)b * CDIM * NTOK;
    const int ti = tid & 31, cq = tid >> 5;
    float ss = 0.f;
    for (int c = cq; c < CDIM; c += 8) {
        float v = xb[(size_t)c * NTOK + t0 + ti];
        tile[ti][c] = v;
        ss += v * v;
    }
    part[cq][ti] = ss;
    __syncthreads();
    if (tid < TT) {
        float s = 0.f;
#pragma unroll
        for (int q = 0; q < 8; ++q) s += part[q][tid];
        rinv_s[tid] = 1.0f / sqrtf(s);
    }
    __syncthreads();
    const int tok = tid >> 3, seg = tid & 7;
    const float ri = rinv_s[tok];
    size_t obase = ((size_t)(b * NTOK + t0 + tok)) * CDIM + seg * 32;
#pragma unroll
    for (int j = 0; j < 4; ++j) {
        u32 w[4];
#pragma unroll
        for (int u = 0; u < 4; ++u) {
            float f0 = tile[tok][seg * 32 + j * 8 + 2 * u] * ri;
            float f1 = tile[tok][seg * 32 + j * 8 + 2 * u + 1] * ri;
            w[u] = f2bf2(f0, f1);
        }
        *(uintx4*)&xn[obase + j * 8] = (uintx4){w[0], w[1], w[2], w[3]};
    }
}

// ---------- fused two-sweep GEMM + softmax ----------
// Block: 64 rows x 4096 cols, K=256. A in regs. B chunks (128 tok x 128 k = 32 KB)
// double-buffered, depth-1 prefetch, counted vmcnt(4), 2 raw barriers per chunk.
// LDS XOR-swizzle: 16B-position p of row tr holds logical 16B-chunk (p ^ (tr&7)).
__global__ __launch_bounds__(512, 2) void attn_kernel(const short* __restrict__ xn,
                                                      float* __restrict__ out) {
    __shared__ short Bs[2][128 * 128];      // 2 x 32 KB
    __shared__ float rowsumLds[BM][4];
    const int tid = threadIdx.x;
    // batch-aligned XCD swizzle: XCD(D)=D%8 -> logical block L in [32*xcd, 32*xcd+32)
    const int D = blockIdx.x;
    const int L = (D & 7) * 32 + (D >> 3);
    const int b = L >> 6;
    const int rb = (L & 63) * BM;
    const short* xnb = xn + (size_t)b * NTOK * CDIM;
    float* outb = out + ((size_t)b << 24);
    const int lane = tid & 63, wid = tid >> 6;     // 8 waves: 2 row x 4 col
    const int wr = (wid >> 2) * 32;                // 0 / 32
    const int wc = (wid & 3) * 32;                 // 0 / 32 / 64 / 96
    const int r0 = lane & 15, kq = lane >> 4;

    // A fragments: rows rb + wr + m*16 + r0, full K=256 in registers
    bf16x8 afr[2][8];
#pragma unroll
    for (int m = 0; m < 2; ++m) {
        const short* arow = xnb + (size_t)(rb + wr + m * 16 + r0) * CDIM;
#pragma unroll
        for (int kc = 0; kc < 8; ++kc)
            afr[m][kc] = *(const bf16x8*)(arow + kc * 32 + kq * 8);
    }

    float psum[2][4] = {{0.f,0.f,0.f,0.f},{0.f,0.f,0.f,0.f}};
    float rinv[2][4];

    // stage chunk t (ct = t>>1, k-half = t&1) into buf t&1; 4 rounds x 32 tokens
    auto stage = [&](int t) {
        const int buf = t & 1, ct = t >> 1, ck = t & 1;
        const int trow_l = tid >> 4;               // 0..31 within round
        const int p = tid & 15;
#pragma unroll
        for (int rr = 0; rr < 4; ++rr) {
            const int trow = rr * 32 + trow_l;
            const int c = p ^ (trow & 7);          // inverse-swizzled source 16B-chunk
            const short* src = xnb + (size_t)(ct * BN + trow) * CDIM + ck * 128 + c * 8;
            gload_lds16(src, &Bs[buf][rr * 4096 + wid * 512]);  // + lane*16B by HW
        }
    };

    for (int sweep = 0; sweep < 2; ++sweep) {
        stage(0);
        floatx4 acc[2][2];
#pragma unroll
        for (int m = 0; m < 2; ++m)
#pragma unroll
            for (int n = 0; n < 2; ++n)
                acc[m][n] = (floatx4){0.f, 0.f, 0.f, 0.f};

        for (int t = 0; t < NCHUNK; ++t) {
            if (t + 1 < NCHUNK) { stage(t + 1); WAITV4; }
            else { WAITV0; }
            __builtin_amdgcn_s_barrier();
            MEMFENCE;

            const short* base = &Bs[t & 1][0];
            const int ck = t & 1;
            __builtin_amdgcn_s_setprio(1);
#pragma unroll
            for (int kk = 0; kk < 4; ++kk) {
                bf16x8 bfr[2];
#pragma unroll
                for (int n = 0; n < 2; ++n) {
                    const int tr = wc + n * 16 + r0;
                    const int p = ((kk << 2) | kq) ^ (tr & 7);
                    bfr[n] = *(const bf16x8*)&base[tr * 128 + p * 8];
                }
                acc[0][0] = __builtin_amdgcn_mfma_f32_16x16x32_bf16(afr[0][ck*4+kk], bfr[0], acc[0][0], 0,0,0);
                acc[1][0] = __builtin_amdgcn_mfma_f32_16x16x32_bf16(afr[1][ck*4+kk], bfr[0], acc[1][0], 0,0,0);
                acc[0][1] = __builtin_amdgcn_mfma_f32_16x16x32_bf16(afr[0][ck*4+kk], bfr[1], acc[0][1], 0,0,0);
                acc[1][1] = __builtin_amdgcn_mfma_f32_16x16x32_bf16(afr[1][ck*4+kk], bfr[1], acc[1][1], 0,0,0);
            }
            __builtin_amdgcn_s_setprio(0);

            if (t & 1) {                            // ct complete
                const int ct = t >> 1;
                if (sweep == 0) {
#pragma unroll
                    for (int m = 0; m < 2; ++m)
#pragma unroll
                        for (int r = 0; r < 4; ++r)
                            psum[m][r] += __expf(acc[m][0][r] - 1.f) + __expf(acc[m][1][r] - 1.f);
                } else {
#pragma unroll
                    for (int m = 0; m < 2; ++m)
#pragma unroll
                        for (int r = 0; r < 4; ++r) {
                            const int row = rb + wr + m * 16 + kq * 4 + r;
                            float* p = outb + ((size_t)row << 12) + ct * BN + wc + r0;
                            __builtin_nontemporal_store(__expf(acc[m][0][r] - 1.f) * rinv[m][r], p);
                            __builtin_nontemporal_store(__expf(acc[m][1][r] - 1.f) * rinv[m][r], p + 16);
                        }
                }
#pragma unroll
                for (int m = 0; m < 2; ++m)
#pragma unroll
                    for (int n = 0; n < 2; ++n)
                        acc[m][n] = (floatx4){0.f, 0.f, 0.f, 0.f};
            }
            MEMFENCE;
            __builtin_amdgcn_s_barrier();           // all waves done reading buf t&1
            MEMFENCE;
        } // t

        if (sweep == 0) {
#pragma unroll
            for (int m = 0; m < 2; ++m)
#pragma unroll
                for (int r = 0; r < 4; ++r) {
                    float v = psum[m][r];
                    v += __shfl_xor(v, 1);
                    v += __shfl_xor(v, 2);
                    v += __shfl_xor(v, 4);
                    v += __shfl_xor(v, 8);
                    if (r0 == 0) rowsumLds[wr + m * 16 + kq * 4 + r][wid & 3] = v;
                }
            __syncthreads();
#pragma unroll
            for (int m = 0; m < 2; ++m)
#pragma unroll
                for (int r = 0; r < 4; ++r) {
                    const int row = wr + m * 16 + kq * 4 + r;
                    rinv[m][r] = 1.0f / (rowsumLds[row][0] + rowsumLds[row][1] +
                                         rowsumLds[row][2] + rowsumLds[row][3]);
                }
            __syncthreads();
        }
    } // sweep
}

extern "C" void kernel_launch(void* const* d_in, const int* in_sizes, int n_in,
                              void* d_out, int out_size, void* d_ws, size_t ws_size,
                              hipStream_t stream) {
    const float* x = (const float*)d_in[0];
    float* out = (float*)d_out;
    short* xn = (short*)d_ws;    // [B][N][C] bf16 = 8 MB

    prep_kernel<<<BATCH * (NTOK / TT), 256, 0, stream>>>(x, xn);

    attn_kernel<<<NTOK / BM * BATCH, 512, 0, stream>>>(xn, out);
}

// Round 5
// 160.133 us; speedup vs baseline: 4.0998x; 2.2836x over previous
//
#include <hip/hip_runtime.h>
#include <hip/hip_bf16.h>

// x [B=4][C=256][N=4096] fp32 -> attention [B][N][N] fp32 (row softmax of cosine sim)
#define BATCH 4
#define CDIM  256
#define NTOK  4096

#define BM 64      // rows per block
#define BN 128     // tokens per chunk; chunk = 128 tok x K=256 = 64 KB, double-buffered

typedef short bf16x8 __attribute__((ext_vector_type(8)));
typedef float floatx4 __attribute__((ext_vector_type(4)));
typedef unsigned int uintx4 __attribute__((ext_vector_type(4)));
typedef unsigned int u32;

__device__ inline u32 f2bf1(float f) {
    u32 u = __float_as_uint(f);
    u += 0x7fffu + ((u >> 16) & 1u);   // RTNE
    return u >> 16;
}
__device__ inline u32 f2bf2(float lo, float hi) { return f2bf1(lo) | (f2bf1(hi) << 16); }

__device__ inline void gload_lds16(const short* g, short* l) {
    __builtin_amdgcn_global_load_lds(
        (const __attribute__((address_space(1))) u32*)g,
        (__attribute__((address_space(3))) u32*)l, 16, 0, 0);
}

// ---------- prep: x [B][C][N] f32 -> xn [B][N][C] bf16, rows normalized to unit L2 ----------
#define TT 32
__global__ __launch_bounds__(256) void prep_kernel(const float* __restrict__ x,
                                                   short* __restrict__ xn) {
    __shared__ float tile[TT][CDIM + 2];
    __shared__ float part[8][TT];
    __shared__ float rinv_s[TT];
    const int tid = threadIdx.x;
    const int blk = blockIdx.x;            // 0..511
    const int b = blk >> 7;
    const int t0 = (blk & 127) * TT;
    const float* xb = x + (size_t)b * CDIM * NTOK;
    const int ti = tid & 31, cq = tid >> 5;
    float ss = 0.f;
    for (int c = cq; c < CDIM; c += 8) {
        float v = xb[(size_t)c * NTOK + t0 + ti];
        tile[ti][c] = v;
        ss += v * v;
    }
    part[cq][ti] = ss;
    __syncthreads();
    if (tid < TT) {
        float s = 0.f;
#pragma unroll
        for (int q = 0; q < 8; ++q) s += part[q][tid];
        rinv_s[tid] = 1.0f / sqrtf(s);
    }
    __syncthreads();
    const int tok = tid >> 3, seg = tid & 7;
    const float ri = rinv_s[tok];
    size_t obase = ((size_t)(b * NTOK + t0 + tok)) * CDIM + seg * 32;
#pragma unroll
    for (int j = 0; j < 4; ++j) {
        u32 w[4];
#pragma unroll
        for (int u = 0; u < 4; ++u) {
            float f0 = tile[tok][seg * 32 + j * 8 + 2 * u] * ri;
            float f1 = tile[tok][seg * 32 + j * 8 + 2 * u + 1] * ri;
            w[u] = f2bf2(f0, f1);
        }
        *(uintx4*)&xn[obase + j * 8] = (uintx4){w[0], w[1], w[2], w[3]};
    }
}

// ---------- fused two-sweep GEMM + softmax ----------
// Block: 64 rows x 4096 cols, K=256. A in regs (STATIC indices only — rule #20).
// B chunk = 128 tok x 256 k as 4 sub-chunks [128][64] (R2's proven 0-conflict
// layout: 16B-position p of row tr holds logical chunk p ^ (tr&7)).
// Double buffer, stage(ct+1) issued BEFORE compute(ct); one __syncthreads per chunk.
__global__ __launch_bounds__(512, 2) void attn_kernel(const short* __restrict__ xn,
                                                      float* __restrict__ out) {
    __shared__ short Bs[2][4][128][64];      // 2 x 64 KB
    __shared__ float rowsumLds[BM][4];
    const int tid = threadIdx.x;
    const int D = blockIdx.x;                // natural order (R2-proven coherence)
    const int b = D >> 6;
    const int rb = (D & 63) * BM;
    const short* xnb = xn + (size_t)b * NTOK * CDIM;
    float* outb = out + ((size_t)b << 24);
    const int lane = tid & 63, wid = tid >> 6;     // 8 waves: 2 row x 4 col
    const int wr = (wid >> 2) * 32;                // 0 / 32
    const int wc = (wid & 3) * 32;                 // 0 / 32 / 64 / 96
    const int r0 = lane & 15, kq = lane >> 4;

    // staging roles (per wave): rows wid*8 .. wid*8+7 (+64 for h=1)
    const int trl0 = (wid << 3) + (lane >> 3);     // 0..63
    const int c8 = (lane & 7) ^ (lane >> 3);       // inverse-swizzled source 16B-chunk

    // A fragments: rows rb + wr + m*16 + r0, full K=256 in registers
    bf16x8 afr[2][8];
#pragma unroll
    for (int m = 0; m < 2; ++m) {
        const short* arow = xnb + (size_t)(rb + wr + m * 16 + r0) * CDIM;
#pragma unroll
        for (int j = 0; j < 8; ++j)
            afr[m][j] = *(const bf16x8*)(arow + j * 32 + kq * 8);
    }

    float psum[2][4] = {{0.f,0.f,0.f,0.f},{0.f,0.f,0.f,0.f}};
    float rinv[2][4];

    // stage chunk ct (128 tok x 256 k) into buffer buf: 8 gload per lane
    auto stage = [&](int ct, int buf) {
        const short* srcBase = xnb + (size_t)(ct * BN) * CDIM;
#pragma unroll
        for (int kc = 0; kc < 4; ++kc)
#pragma unroll
            for (int h = 0; h < 2; ++h) {
                const short* s = srcBase + (size_t)(h * 64 + trl0) * CDIM + kc * 64 + c8 * 8;
                gload_lds16(s, &Bs[buf][kc][h * 64 + (wid << 3)][0]);
            }
    };

    for (int sweep = 0; sweep < 2; ++sweep) {
        stage(0, 0);
        __syncthreads();                      // buffer 0 ready

        for (int ct = 0; ct < 32; ++ct) {
            const int cur = ct & 1;
            if (ct + 1 < 32) stage(ct + 1, cur ^ 1);   // flies during compute

            floatx4 acc[2][2];
#pragma unroll
            for (int m = 0; m < 2; ++m)
#pragma unroll
                for (int n = 0; n < 2; ++n)
                    acc[m][n] = (floatx4){0.f, 0.f, 0.f, 0.f};

            __builtin_amdgcn_s_setprio(1);
#pragma unroll
            for (int kc = 0; kc < 4; ++kc) {
#pragma unroll
                for (int kk = 0; kk < 2; ++kk) {
                    bf16x8 bfr[2];
#pragma unroll
                    for (int n = 0; n < 2; ++n) {
                        const int tr = wc + n * 16 + r0;
                        const int p = ((kk << 2) | kq) ^ (tr & 7);
                        bfr[n] = *(const bf16x8*)&Bs[cur][kc][tr][p * 8];
                    }
                    acc[0][0] = __builtin_amdgcn_mfma_f32_16x16x32_bf16(afr[0][kc*2+kk], bfr[0], acc[0][0], 0,0,0);
                    acc[1][0] = __builtin_amdgcn_mfma_f32_16x16x32_bf16(afr[1][kc*2+kk], bfr[0], acc[1][0], 0,0,0);
                    acc[0][1] = __builtin_amdgcn_mfma_f32_16x16x32_bf16(afr[0][kc*2+kk], bfr[1], acc[0][1], 0,0,0);
                    acc[1][1] = __builtin_amdgcn_mfma_f32_16x16x32_bf16(afr[1][kc*2+kk], bfr[1], acc[1][1], 0,0,0);
                }
            }
            __builtin_amdgcn_s_setprio(0);

            if (sweep == 0) {
#pragma unroll
                for (int m = 0; m < 2; ++m)
#pragma unroll
                    for (int r = 0; r < 4; ++r)
                        psum[m][r] += __expf(acc[m][0][r] - 1.f) + __expf(acc[m][1][r] - 1.f);
            } else {
#pragma unroll
                for (int m = 0; m < 2; ++m)
#pragma unroll
                    for (int r = 0; r < 4; ++r) {
                        const int row = rb + wr + m * 16 + kq * 4 + r;
                        float* p = outb + ((size_t)row << 12) + (ct << 7) + wc + r0;
                        __builtin_nontemporal_store(__expf(acc[m][0][r] - 1.f) * rinv[m][r], p);
                        __builtin_nontemporal_store(__expf(acc[m][1][r] - 1.f) * rinv[m][r], p + 16);
                    }
            }
            __syncthreads();                  // drains stage(ct+1); buffer swap safe
        } // ct

        if (sweep == 0) {
#pragma unroll
            for (int m = 0; m < 2; ++m)
#pragma unroll
                for (int r = 0; r < 4; ++r) {
                    float v = psum[m][r];
                    v += __shfl_xor(v, 1);
                    v += __shfl_xor(v, 2);
                    v += __shfl_xor(v, 4);
                    v += __shfl_xor(v, 8);
                    if (r0 == 0) rowsumLds[wr + m * 16 + kq * 4 + r][wid & 3] = v;
                }
            __syncthreads();
#pragma unroll
            for (int m = 0; m < 2; ++m)
#pragma unroll
                for (int r = 0; r < 4; ++r) {
                    const int row = wr + m * 16 + kq * 4 + r;
                    rinv[m][r] = 1.0f / (rowsumLds[row][0] + rowsumLds[row][1] +
                                         rowsumLds[row][2] + rowsumLds[row][3]);
                }
            __syncthreads();
        }
    } // sweep
}

extern "C" void kernel_launch(void* const* d_in, const int* in_sizes, int n_in,
                              void* d_out, int out_size, void* d_ws, size_t ws_size,
                              hipStream_t stream) {
    const float* x = (const float*)d_in[0];
    float* out = (float*)d_out;
    short* xn = (short*)d_ws;    // [B][N][C] bf16 = 8 MB

    prep_kernel<<<BATCH * (NTOK / TT), 256, 0, stream>>>(x, xn);

    attn_kernel<<<NTOK / BM * BATCH, 512, 0, stream>>>(xn, out);
}